// Round 4
// baseline (542.760 us; speedup 1.0000x reference)
//
#include <hip/hip_runtime.h>

// ---------------------------------------------------------------------------
// Attention: y = softmax( (xWq^T)(xWk^T)^T / sqrt(128) ) (xWv^T)
// B=4, N=4096, H=OUT=128. fp32 I/O, bf16 MFMA compute.
//
// R10:
//  flash: R9's 4-qt/wave spilled (VGPR 224 + 90MB scratch writes) -- q-tiles
//  per wave is register-capped at 2 (proven 128 VGPR). R8's 51us = ~55% pipe
//  idle: exposed latency at 2 waves/SIMD. Same traffic, same inner loop, but
//  8 waves/block x 8-way key split -> 16 waves/CU (4/SIMD, VGPR 128 = exact
//  cap), 2 blocks/CU @ 66KB LDS. Combine = 7 partials, two qt-rounds.
//  proj: byte-identical to R8.
// ---------------------------------------------------------------------------

typedef __bf16 bf16;
typedef __attribute__((ext_vector_type(8))) __bf16 bf16x8;
typedef __attribute__((ext_vector_type(4))) __bf16 bf16x4;
typedef __attribute__((ext_vector_type(4))) float f32x4;

#define MFMA16(a, b, c) __builtin_amdgcn_mfma_f32_16x16x32_bf16(a, b, c, 0, 0, 0)
#define SB0() __builtin_amdgcn_sched_barrier(0)

#if __has_builtin(__builtin_amdgcn_exp2f)
#define EXP2F(x) __builtin_amdgcn_exp2f(x)
#else
#define EXP2F(x) exp2f(x)
#endif

static constexpr int BATCH = 4;
static constexpr int N = 4096;
static constexpr int D = 128;
static constexpr int ROWS = BATCH * N;  // 16384
// fold 1/sqrt(128) and log2(e) into q so softmax is raw exp2
static constexpr float QSCALE = 0.088388347648318447f * 1.4426950408889634f;

__device__ inline bf16x8 ld8_f32_bf16(const float* __restrict__ p) {
    f32x4 a = *(const f32x4*)p;
    f32x4 b = *(const f32x4*)(p + 4);
    bf16x8 r;
    r[0] = (bf16)a[0]; r[1] = (bf16)a[1]; r[2] = (bf16)a[2]; r[3] = (bf16)a[3];
    r[4] = (bf16)b[0]; r[5] = (bf16)b[1]; r[6] = (bf16)b[2]; r[7] = (bf16)b[3];
    return r;
}

// Fragment layouts (16x16x32 bf16; lane = quad*16 + l16):
//  qf/kf: (tile,row,d) -> ((tile*4 + (d>>5))*64 + ((d&31)>>3)*16 + row)*8 + (d&7)
//  vf (kappa-permuted): fragment (g64, ot, m), lane (quad, o15), elem j holds
//     V[64*g64 + kappa][ot*16 + o15] with
//     kappa = 32*m + (j<4 ? quad*4 + j : 16 + quad*4 + (j-4))
//  This matches the per-lane register order of S^T = mfma(K,Q) after exp2:
//     lane (quad,l16) holds P[q=l16][k = nt*16 + quad*4 + rg]  (nt=2m+j/4, rg=j&3)

// ---------------------------------------------------------------------------
// proj_all: grid 768 x 256. Block = (phase, 64-token group); 4 waves, one
// 16-token tile each. Stage W[phase] coalesced into LDS fragments (one
// __syncthreads), MFMA, transpose C through per-wave scratch, store.
// 52KB LDS -> 3 blocks/CU = 12 waves/CU.
// ---------------------------------------------------------------------------
__global__ __launch_bounds__(256) void proj_all(const float* __restrict__ x,
                                                const float* __restrict__ Wq,
                                                const float* __restrict__ Wk,
                                                const float* __restrict__ Wv,
                                                bf16* __restrict__ qf,
                                                bf16* __restrict__ kf,
                                                bf16* __restrict__ vf) {
    __shared__ __attribute__((aligned(16))) bf16 Wl[D * D];     // 32 KB
    __shared__ __attribute__((aligned(16))) bf16 Scr[4][2560];  // 20 KB

    const int lane = threadIdx.x & 63;
    const int w = threadIdx.x >> 6;
    const int l16 = lane & 15;
    const int quad = lane >> 4;
    const int phase = (int)(blockIdx.x % 3u);   // 0=Q 1=K 2=V
    const int group = (int)(blockIdx.x / 3u);   // 0..255 = 64-token group
    const int tile = group * 4 + w;             // global 16-token tile
    const int tok0 = tile << 4;

    const float* __restrict__ W = (phase == 0) ? Wq : (phase == 1) ? Wk : Wv;

    // ---- stage W into LDS in fragment layout (coalesced fp32 reads) ----
    {
        const int r = threadIdx.x >> 1;
        const int c0 = (threadIdx.x & 1) * 64;
#pragma unroll
        for (int g = 0; g < 8; g++) {
            const int h = c0 + g * 8;
            bf16x8 v = ld8_f32_bf16(W + r * D + h);
            const int frag = (r >> 4) * 4 + (h >> 5);
            const int ln = ((h & 31) >> 3) * 16 + (r & 15);
            *(bf16x8*)&Wl[(frag * 64 + ln) * 8] = v;
        }
    }

    // x fragments (A layout; identical lane layout serves as B too)
    bf16x8 xa[4];
#pragma unroll
    for (int ks = 0; ks < 4; ks++)
        xa[ks] = ld8_f32_bf16(x + (size_t)(tok0 + l16) * D + ks * 32 + quad * 8);

    __syncthreads();

    bf16* __restrict__ T = Scr[w];

    if (phase < 2) {
        // ---- Q or K: A = x, B = W fragment ----
        bf16* __restrict__ outp = (phase == 0) ? qf : kf;
        const float scale = (phase == 0) ? QSCALE : 1.0f;
#pragma unroll
        for (int nt = 0; nt < 8; nt++) {
            f32x4 acc = {0.f, 0.f, 0.f, 0.f};
#pragma unroll
            for (int ks = 0; ks < 4; ks++) {
                bf16x8 bw = *(const bf16x8*)&Wl[((nt * 4 + ks) * 64 + lane) * 8];
                acc = MFMA16(xa[ks], bw, acc);
            }
            // C: row = token = quad*4+rg, col = n = nt*16+l16
#pragma unroll
            for (int rg = 0; rg < 4; rg++)
                T[(quad * 4 + rg) * 136 + nt * 16 + l16] = (bf16)(acc[rg] * scale);
        }
        // readback fragments (tok = l16), coalesced 1KB stores
#pragma unroll
        for (int ks = 0; ks < 4; ks++) {
            bf16x8 frag = *(const bf16x8*)&T[l16 * 136 + ks * 32 + quad * 8];
            *(bf16x8*)(outp + (((size_t)tile * 4 + ks) * 64 + lane) * 8) = frag;
        }
    } else {
        // ---- V: A = Wv fragment (row = o), B = x (col = token) ----
#pragma unroll
        for (int mt = 0; mt < 8; mt++) {
            f32x4 acc = {0.f, 0.f, 0.f, 0.f};
#pragma unroll
            for (int ks = 0; ks < 4; ks++) {
                bf16x8 aw = *(const bf16x8*)&Wl[((mt * 4 + ks) * 64 + lane) * 8];
                acc = MFMA16(aw, xa[ks], acc);
            }
            // C: row = o = mt*16+quad*4+rg, col = token = l16  ->  T[o][tok]
#pragma unroll
            for (int rg = 0; rg < 4; rg++)
                T[(mt * 16 + quad * 4 + rg) * 20 + l16] = (bf16)acc[rg];
        }
        // This 16-token tile covers kappa in [16*t4, 16*t4+16) of its 64-key
        // group: exactly the jh half (bf16x4) of mfma m for all quads.
        const int g64 = tok0 >> 6;
        const int t4 = (tok0 >> 4) & 3;
        const int m = t4 >> 1;
        const int jh = t4 & 1;
#pragma unroll
        for (int ot = 0; ot < 8; ot++) {
            bf16x4 v4 = *(const bf16x4*)&T[(ot * 16 + l16) * 20 + quad * 4];
            *(bf16x4*)(vf + ((((size_t)g64 * 8 + ot) * 2 + m) * 64 + lane) * 8 +
                       jh * 4) = v4;
        }
    }
}

// ---------------------------------------------------------------------------
// flash: grid 512 x 512 (8 waves). Block = 32 q-rows (2 tiles, shared by all
// waves); wave w = key-split w (512 keys, 8 iters of 64). 16 waves/CU
// (4/SIMD) hides L2 latency; traffic unchanged vs R8. Swapped QK^T,
// in-register P, kappa-permuted V. 7-partial fp32 combine, two qt-rounds.
// ---------------------------------------------------------------------------
__global__ __launch_bounds__(512) __attribute__((amdgpu_waves_per_eu(4, 4)))
void flash(const bf16* __restrict__ qf,
           const bf16* __restrict__ kf,
           const bf16* __restrict__ vf,
           float* __restrict__ out) {
    __shared__ __attribute__((aligned(16))) float Rs[7][16 * 148];  // 66304B

    const int lane = threadIdx.x & 63;
    const int w = threadIdx.x >> 6;  // 0..7 = key split
    const int l16 = lane & 15;
    const int quad = lane >> 4;

    // XCD swizzle: bid%8 = XCD; 2 XCDs per batch -> K/V (2MB) L2-resident.
    const int lo = blockIdx.x & 7;
    const int hi = blockIdx.x >> 3;
    const int batch = lo >> 1;
    const int qpair = hi * 2 + (lo & 1);       // 0..127
    const int qtg0 = batch * 256 + qpair * 2;  // global q-tile of tile 0

    bf16x8 aq[2][4];
#pragma unroll
    for (int qt = 0; qt < 2; qt++)
#pragma unroll
        for (int ks = 0; ks < 4; ks++)
            aq[qt][ks] =
                *(const bf16x8*)(qf + (((size_t)(qtg0 + qt) * 4 + ks) * 64 + lane) * 8);

    f32x4 oacc[2][9];
#pragma unroll
    for (int qt = 0; qt < 2; qt++)
#pragma unroll
        for (int i = 0; i < 9; i++) oacc[qt][i] = (f32x4){0.f, 0.f, 0.f, 0.f};

    bf16x8 vone;
#pragma unroll
    for (int j = 0; j < 8; j++) vone[j] = (bf16)1.0f;

    const int kb0 = w * (N / 8);  // 512 keys per wave

    // preload K batch for it=0
    bf16x8 bk[4][4];
    {
        const int ktile = batch * 256 + (kb0 >> 4);
#pragma unroll
        for (int nt = 0; nt < 4; nt++)
#pragma unroll
            for (int ks = 0; ks < 4; ks++)
                bk[nt][ks] = *(const bf16x8*)(kf +
                    (((size_t)(ktile + nt) * 4 + ks) * 64 + lane) * 8);
    }
    SB0();

#pragma unroll 1
    for (int it = 0; it < 8; it++) {
        const int kb = kb0 + it * 64;
        const size_t g64v = (size_t)batch * 64 + (kb >> 6);

        // ---- V batch 1 (ot 0..3) issued early: covered by QK + exp2 ----
        bf16x8 bv1[4][2];
#pragma unroll
        for (int ot = 0; ot < 4; ot++)
#pragma unroll
            for (int m = 0; m < 2; m++)
                bv1[ot][m] =
                    *(const bf16x8*)(vf + (((g64v * 8 + ot) * 2 + m) * 64 + lane) * 8);
        SB0();

        // ---- S^T = k.q'' (shared bk across both q-tiles) ----
        f32x4 sv[2][4];
#pragma unroll
        for (int qt = 0; qt < 2; qt++)
#pragma unroll
            for (int nt = 0; nt < 4; nt++) sv[qt][nt] = (f32x4){0.f, 0.f, 0.f, 0.f};
        __builtin_amdgcn_s_setprio(1);
#pragma unroll
        for (int ks = 0; ks < 4; ks++)
#pragma unroll
            for (int nt = 0; nt < 4; nt++) {
                sv[0][nt] = MFMA16(bk[nt][ks], aq[0][ks], sv[0][nt]);
                sv[1][nt] = MFMA16(bk[nt][ks], aq[1][ks], sv[1][nt]);
            }
        __builtin_amdgcn_s_setprio(0);
        SB0();

        // ---- V batch 2 (ot 4..7) ----
        bf16x8 bv2[4][2];
#pragma unroll
        for (int ot = 0; ot < 4; ot++)
#pragma unroll
            for (int m = 0; m < 2; m++)
                bv2[ot][m] = *(const bf16x8*)(vf +
                    (((g64v * 8 + ot + 4) * 2 + m) * 64 + lane) * 8);
        SB0();

        // ---- P = exp2(S^T) -> A-fragments, fully in-register ----
        bf16x8 ap[2][2];
#pragma unroll
        for (int qt = 0; qt < 2; qt++)
#pragma unroll
            for (int m = 0; m < 2; m++) {
                bf16x8 t;
#pragma unroll
                for (int j = 0; j < 4; j++) {
                    t[j] = (bf16)EXP2F(sv[qt][2 * m][j]);
                    t[j + 4] = (bf16)EXP2F(sv[qt][2 * m + 1][j]);
                }
                ap[qt][m] = t;
            }
        SB0();

        // ---- prefetch next iter's K (bk dead after QK) ----
        {
            const int itn = (it < 7) ? it + 1 : 7;
            const int kbn = kb0 + itn * 64;
            const int ktn = batch * 256 + (kbn >> 4);
#pragma unroll
            for (int nt = 0; nt < 4; nt++)
#pragma unroll
                for (int ks = 0; ks < 4; ks++)
                    bk[nt][ks] = *(const bf16x8*)(kf +
                        (((size_t)(ktn + nt) * 4 + ks) * 64 + lane) * 8);
        }
        SB0();

        // ---- O += P.V  (D: row=q=quad*4+rg, col=o=l16) ----
        __builtin_amdgcn_s_setprio(1);
#pragma unroll
        for (int ot = 0; ot < 4; ot++)
#pragma unroll
            for (int m = 0; m < 2; m++) {
                oacc[0][ot] = MFMA16(ap[0][m], bv1[ot][m], oacc[0][ot]);
                oacc[1][ot] = MFMA16(ap[1][m], bv1[ot][m], oacc[1][ot]);
            }
#pragma unroll
        for (int ot = 0; ot < 4; ot++)
#pragma unroll
            for (int m = 0; m < 2; m++) {
                oacc[0][ot + 4] = MFMA16(ap[0][m], bv2[ot][m], oacc[0][ot + 4]);
                oacc[1][ot + 4] = MFMA16(ap[1][m], bv2[ot][m], oacc[1][ot + 4]);
            }
#pragma unroll
        for (int qt = 0; qt < 2; qt++)
#pragma unroll
            for (int m = 0; m < 2; m++)
                oacc[qt][8] = MFMA16(ap[qt][m], vone, oacc[qt][8]);
        __builtin_amdgcn_s_setprio(0);
        SB0();
    }

    // ---- combine the 8 key-split partials through LDS (fp32), 2 rounds ----
#pragma unroll 1
    for (int p = 0; p < 2; p++) {
        __syncthreads();  // p=0: main loop done; p=1: w0 done reading round 0
        if (w > 0) {
            float* __restrict__ dst = &Rs[w - 1][0];
#pragma unroll
            for (int t = 0; t < 9; t++)
#pragma unroll
                for (int rg = 0; rg < 4; rg++)
                    dst[(quad * 4 + rg) * 148 + t * 16 + l16] = oacc[p][t][rg];
        }
        __syncthreads();
        if (w == 0) {
#pragma unroll 1
            for (int sIdx = 0; sIdx < 7; sIdx++) {
                const float* __restrict__ src = &Rs[sIdx][0];
#pragma unroll
                for (int t = 0; t < 9; t++)
#pragma unroll
                    for (int rg = 0; rg < 4; rg++)
                        oacc[p][t][rg] += src[(quad * 4 + rg) * 148 + t * 16 + l16];
            }
#pragma unroll
            for (int rg = 0; rg < 4; rg++) {
                const float rl = 1.0f / oacc[p][8][rg];
                float* __restrict__ yrow =
                    out + (((size_t)(qtg0 + p)) * 16 + quad * 4 + rg) * D;
#pragma unroll
                for (int t = 0; t < 8; t++)
                    yrow[t * 16 + l16] = oacc[p][t][rg] * rl;
            }
        }
    }
}

// ---------------------------------------------------------------------------
extern "C" void kernel_launch(void* const* d_in, const int* in_sizes, int n_in,
                              void* d_out, int out_size, void* d_ws, size_t ws_size,
                              hipStream_t stream) {
    const float* x = (const float*)d_in[0];
    const float* Wq = (const float*)d_in[1];
    const float* Wk = (const float*)d_in[2];
    const float* Wv = (const float*)d_in[3];
    float* y = (float*)d_out;

    bf16* qf = (bf16*)d_ws;            // 4MB
    bf16* kf = qf + (size_t)ROWS * D;  // 4MB
    bf16* vf = kf + (size_t)ROWS * D;  // 4MB (kappa-permuted fragment layout)

    proj_all<<<768, 256, 0, stream>>>(x, Wq, Wk, Wv, qf, kf, vf);
    flash<<<512, 512, 0, stream>>>(qf, kf, vf, y);
}

// Round 6
// 124.423 us; speedup vs baseline: 4.3622x; 4.3622x over previous
//
#include <hip/hip_runtime.h>

// ---------------------------------------------------------------------------
// Attention: y = softmax( (xWq^T)(xWk^T)^T / sqrt(128) ) (xWv^T)
// B=4, N=4096, H=OUT=128. fp32 I/O, bf16 MFMA compute.
//
// R12: R11 with the K-staging address bug fixed. In kf's fragment layout one
//  16-key tile = 2048 ELEMENTS (4 frags x 64 lanes x 8); R11 staged from
//  kt0*4096 -> read garbage K for every tile after the first (absmax 0.54).
//  Fix: kt0*2048 / ktn*2048. Everything else identical to R11:
//  flash: grid 256 = 128 q-groups x 2 key-splits; 4 waves x 2 q-tiles (proven
//  R8 reg layout) all iterate the SAME 64-key tiles: K staged once/block into
//  dbuf LDS (reg-staged, issue-early/write-late, 1 syncthreads/iter), V loads
//  L1-shared across the 4 waves. L2 ingest 1.07GB -> ~256MB. Blocks write
//  fp32 partials (O + rowsum); comb kernel adds 2 splits and divides.
//  proj: byte-identical to R8.
// ---------------------------------------------------------------------------

typedef __bf16 bf16;
typedef __attribute__((ext_vector_type(8))) __bf16 bf16x8;
typedef __attribute__((ext_vector_type(4))) __bf16 bf16x4;
typedef __attribute__((ext_vector_type(4))) float f32x4;

#define MFMA16(a, b, c) __builtin_amdgcn_mfma_f32_16x16x32_bf16(a, b, c, 0, 0, 0)
#define SB0() __builtin_amdgcn_sched_barrier(0)

#if __has_builtin(__builtin_amdgcn_exp2f)
#define EXP2F(x) __builtin_amdgcn_exp2f(x)
#else
#define EXP2F(x) exp2f(x)
#endif

static constexpr int BATCH = 4;
static constexpr int N = 4096;
static constexpr int D = 128;
static constexpr int ROWS = BATCH * N;  // 16384
// fold 1/sqrt(128) and log2(e) into q so softmax is raw exp2
static constexpr float QSCALE = 0.088388347648318447f * 1.4426950408889634f;

__device__ inline bf16x8 ld8_f32_bf16(const float* __restrict__ p) {
    f32x4 a = *(const f32x4*)p;
    f32x4 b = *(const f32x4*)(p + 4);
    bf16x8 r;
    r[0] = (bf16)a[0]; r[1] = (bf16)a[1]; r[2] = (bf16)a[2]; r[3] = (bf16)a[3];
    r[4] = (bf16)b[0]; r[5] = (bf16)b[1]; r[6] = (bf16)b[2]; r[7] = (bf16)b[3];
    return r;
}

// Fragment layouts (16x16x32 bf16; lane = quad*16 + l16):
//  qf/kf: (tile,row,d) -> ((tile*4 + (d>>5))*64 + ((d&31)>>3)*16 + row)*8 + (d&7)
//         => one 16-row tile = 4*64*8 = 2048 elements.
//  vf (kappa-permuted): fragment (g64, ot, m), lane (quad, o15), elem j holds
//     V[64*g64 + kappa][ot*16 + o15] with
//     kappa = 32*m + (j<4 ? quad*4 + j : 16 + quad*4 + (j-4))
//  This matches the per-lane register order of S^T = mfma(K,Q) after exp2:
//     lane (quad,l16) holds P[q=l16][k = nt*16 + quad*4 + rg]  (nt=2m+j/4, rg=j&3)

// ---------------------------------------------------------------------------
// proj_all: grid 768 x 256. Block = (phase, 64-token group); 4 waves, one
// 16-token tile each. Stage W[phase] coalesced into LDS fragments (one
// __syncthreads), MFMA, transpose C through per-wave scratch, store.
// ---------------------------------------------------------------------------
__global__ __launch_bounds__(256) void proj_all(const float* __restrict__ x,
                                                const float* __restrict__ Wq,
                                                const float* __restrict__ Wk,
                                                const float* __restrict__ Wv,
                                                bf16* __restrict__ qf,
                                                bf16* __restrict__ kf,
                                                bf16* __restrict__ vf) {
    __shared__ __attribute__((aligned(16))) bf16 Wl[D * D];     // 32 KB
    __shared__ __attribute__((aligned(16))) bf16 Scr[4][2560];  // 20 KB

    const int lane = threadIdx.x & 63;
    const int w = threadIdx.x >> 6;
    const int l16 = lane & 15;
    const int quad = lane >> 4;
    const int phase = (int)(blockIdx.x % 3u);   // 0=Q 1=K 2=V
    const int group = (int)(blockIdx.x / 3u);   // 0..255 = 64-token group
    const int tile = group * 4 + w;             // global 16-token tile
    const int tok0 = tile << 4;

    const float* __restrict__ W = (phase == 0) ? Wq : (phase == 1) ? Wk : Wv;

    // ---- stage W into LDS in fragment layout (coalesced fp32 reads) ----
    {
        const int r = threadIdx.x >> 1;
        const int c0 = (threadIdx.x & 1) * 64;
#pragma unroll
        for (int g = 0; g < 8; g++) {
            const int h = c0 + g * 8;
            bf16x8 v = ld8_f32_bf16(W + r * D + h);
            const int frag = (r >> 4) * 4 + (h >> 5);
            const int ln = ((h & 31) >> 3) * 16 + (r & 15);
            *(bf16x8*)&Wl[(frag * 64 + ln) * 8] = v;
        }
    }

    // x fragments (A layout; identical lane layout serves as B too)
    bf16x8 xa[4];
#pragma unroll
    for (int ks = 0; ks < 4; ks++)
        xa[ks] = ld8_f32_bf16(x + (size_t)(tok0 + l16) * D + ks * 32 + quad * 8);

    __syncthreads();

    bf16* __restrict__ T = Scr[w];

    if (phase < 2) {
        // ---- Q or K: A = x, B = W fragment ----
        bf16* __restrict__ outp = (phase == 0) ? qf : kf;
        const float scale = (phase == 0) ? QSCALE : 1.0f;
#pragma unroll
        for (int nt = 0; nt < 8; nt++) {
            f32x4 acc = {0.f, 0.f, 0.f, 0.f};
#pragma unroll
            for (int ks = 0; ks < 4; ks++) {
                bf16x8 bw = *(const bf16x8*)&Wl[((nt * 4 + ks) * 64 + lane) * 8];
                acc = MFMA16(xa[ks], bw, acc);
            }
            // C: row = token = quad*4+rg, col = n = nt*16+l16
#pragma unroll
            for (int rg = 0; rg < 4; rg++)
                T[(quad * 4 + rg) * 136 + nt * 16 + l16] = (bf16)(acc[rg] * scale);
        }
        // readback fragments (tok = l16), coalesced 1KB stores
#pragma unroll
        for (int ks = 0; ks < 4; ks++) {
            bf16x8 frag = *(const bf16x8*)&T[l16 * 136 + ks * 32 + quad * 8];
            *(bf16x8*)(outp + (((size_t)tile * 4 + ks) * 64 + lane) * 8) = frag;
        }
    } else {
        // ---- V: A = Wv fragment (row = o), B = x (col = token) ----
#pragma unroll
        for (int mt = 0; mt < 8; mt++) {
            f32x4 acc = {0.f, 0.f, 0.f, 0.f};
#pragma unroll
            for (int ks = 0; ks < 4; ks++) {
                bf16x8 aw = *(const bf16x8*)&Wl[((mt * 4 + ks) * 64 + lane) * 8];
                acc = MFMA16(aw, xa[ks], acc);
            }
            // C: row = o = mt*16+quad*4+rg, col = token = l16  ->  T[o][tok]
#pragma unroll
            for (int rg = 0; rg < 4; rg++)
                T[(mt * 16 + quad * 4 + rg) * 20 + l16] = (bf16)acc[rg];
        }
        const int g64 = tok0 >> 6;
        const int t4 = (tok0 >> 4) & 3;
        const int m = t4 >> 1;
        const int jh = t4 & 1;
#pragma unroll
        for (int ot = 0; ot < 8; ot++) {
            bf16x4 v4 = *(const bf16x4*)&T[(ot * 16 + l16) * 20 + quad * 4];
            *(bf16x4*)(vf + ((((size_t)g64 * 8 + ot) * 2 + m) * 64 + lane) * 8 +
                       jh * 4) = v4;
        }
    }
}

// ---------------------------------------------------------------------------
// flash: grid 256 x 256 (4 waves). bid -> (batch, split, qg): block owns
// 128 q-rows (4 waves x 2 q-tiles) and keys [split*2048, +2048) (32 iters
// of 64). All 4 waves consume the SAME key tile each iter: K double-buffered
// in LDS (reg-staged: loads issued at iter top, ds_write after PV, one
// __syncthreads/iter), V read from global (L1-shared across waves).
// Partials (O + rowsum) written fp32 to workspace; comb kernel finishes.
// ---------------------------------------------------------------------------
__global__ __launch_bounds__(256) __attribute__((amdgpu_waves_per_eu(2, 2)))
void flash(const bf16* __restrict__ qf,
           const bf16* __restrict__ kf,
           const bf16* __restrict__ vf,
           float* __restrict__ po,
           float* __restrict__ ps) {
    __shared__ __attribute__((aligned(16))) bf16 kbuf[2][8192];  // 2 x 16 KB

    const int lane = threadIdx.x & 63;
    const int w = threadIdx.x >> 6;  // 0..3 = q-owner wave
    const int l16 = lane & 15;
    const int quad = lane >> 4;

    // XCD swizzle: bid%8 -> (batch, split); 2 XCDs per batch.
    const int lo = blockIdx.x & 7;
    const int batch = lo >> 1;
    const int split = lo & 1;
    const int qg = blockIdx.x >> 3;            // 0..31
    const int qtg0 = batch * 256 + qg * 8 + w * 2;

    bf16x8 aq[2][4];
#pragma unroll
    for (int qt = 0; qt < 2; qt++)
#pragma unroll
        for (int ks = 0; ks < 4; ks++)
            aq[qt][ks] =
                *(const bf16x8*)(qf + (((size_t)(qtg0 + qt) * 4 + ks) * 64 + lane) * 8);

    f32x4 oacc[2][9];
#pragma unroll
    for (int qt = 0; qt < 2; qt++)
#pragma unroll
        for (int i = 0; i < 9; i++) oacc[qt][i] = (f32x4){0.f, 0.f, 0.f, 0.f};

    bf16x8 vone;
#pragma unroll
    for (int j = 0; j < 8; j++) vone[j] = (bf16)1.0f;

    const int kb0 = split * (N / 2);  // 2048 keys per block
    bf16* __restrict__ kb_lds = (bf16*)kbuf;

    // ---- prologue: stage it=0 K tile (16 KB) into kbuf[0] ----
    // fragment (nt=c, ks=w) of 16-key tile (kt0+c): kf elem offset
    // (kt0+c)*2048 + w*512  ==  kt0*2048 + ((c*4+w)*64+lane)*8 (lane part).
    {
        const int kt0 = batch * 256 + (kb0 >> 4);
        bf16x8 kreg[4];
#pragma unroll
        for (int c = 0; c < 4; c++)
            kreg[c] = *(const bf16x8*)(kf + (size_t)kt0 * 2048 +
                                       ((c * 4 + w) * 64 + lane) * 8);
#pragma unroll
        for (int c = 0; c < 4; c++)
            *(bf16x8*)(kb_lds + ((c * 4 + w) * 64 + lane) * 8) = kreg[c];
    }
    __syncthreads();

#pragma unroll 1
    for (int it = 0; it < 32; it++) {
        const int kb = kb0 + it * 64;
        const int cur = it & 1;
        const size_t g64v = (size_t)batch * 64 + (kb >> 6);
        bf16* __restrict__ kcur = kb_lds + cur * 8192;

        // ---- early: issue next K tile loads (consumed after PV) ----
        bf16x8 kreg[4];
        {
            const int itn = (it < 31) ? it + 1 : 31;
            const int ktn = batch * 256 + ((kb0 + itn * 64) >> 4);
#pragma unroll
            for (int c = 0; c < 4; c++)
                kreg[c] = *(const bf16x8*)(kf + (size_t)ktn * 2048 +
                                           ((c * 4 + w) * 64 + lane) * 8);
        }
        SB0();

        // ---- V batch 1 (ot 0..3), L1-shared across waves ----
        bf16x8 bv1[4][2];
#pragma unroll
        for (int ot = 0; ot < 4; ot++)
#pragma unroll
            for (int m = 0; m < 2; m++)
                bv1[ot][m] =
                    *(const bf16x8*)(vf + (((g64v * 8 + ot) * 2 + m) * 64 + lane) * 8);
        SB0();

        // ---- S^T = k.q'' with K fragments from LDS ----
        f32x4 sv[2][4];
#pragma unroll
        for (int qt = 0; qt < 2; qt++)
#pragma unroll
            for (int nt = 0; nt < 4; nt++) sv[qt][nt] = (f32x4){0.f, 0.f, 0.f, 0.f};
        __builtin_amdgcn_s_setprio(1);
#pragma unroll
        for (int ks = 0; ks < 4; ks++)
#pragma unroll
            for (int nt = 0; nt < 4; nt++) {
                bf16x8 bk = *(const bf16x8*)(kcur + ((nt * 4 + ks) * 64 + lane) * 8);
                sv[0][nt] = MFMA16(bk, aq[0][ks], sv[0][nt]);
                sv[1][nt] = MFMA16(bk, aq[1][ks], sv[1][nt]);
            }
        __builtin_amdgcn_s_setprio(0);
        SB0();

        // ---- V batch 2 (ot 4..7) ----
        bf16x8 bv2[4][2];
#pragma unroll
        for (int ot = 0; ot < 4; ot++)
#pragma unroll
            for (int m = 0; m < 2; m++)
                bv2[ot][m] = *(const bf16x8*)(vf +
                    (((g64v * 8 + ot + 4) * 2 + m) * 64 + lane) * 8);
        SB0();

        // ---- P = exp2(S^T) -> A-fragments, in-register ----
        bf16x8 ap[2][2];
#pragma unroll
        for (int qt = 0; qt < 2; qt++)
#pragma unroll
            for (int m = 0; m < 2; m++) {
                bf16x8 t;
#pragma unroll
                for (int j = 0; j < 4; j++) {
                    t[j] = (bf16)EXP2F(sv[qt][2 * m][j]);
                    t[j + 4] = (bf16)EXP2F(sv[qt][2 * m + 1][j]);
                }
                ap[qt][m] = t;
            }
        SB0();

        // ---- O += P.V ----
        __builtin_amdgcn_s_setprio(1);
#pragma unroll
        for (int ot = 0; ot < 4; ot++)
#pragma unroll
            for (int m = 0; m < 2; m++) {
                oacc[0][ot] = MFMA16(ap[0][m], bv1[ot][m], oacc[0][ot]);
                oacc[1][ot] = MFMA16(ap[1][m], bv1[ot][m], oacc[1][ot]);
            }
#pragma unroll
        for (int ot = 0; ot < 4; ot++)
#pragma unroll
            for (int m = 0; m < 2; m++) {
                oacc[0][ot + 4] = MFMA16(ap[0][m], bv2[ot][m], oacc[0][ot + 4]);
                oacc[1][ot + 4] = MFMA16(ap[1][m], bv2[ot][m], oacc[1][ot + 4]);
            }
#pragma unroll
        for (int qt = 0; qt < 2; qt++)
#pragma unroll
            for (int m = 0; m < 2; m++)
                oacc[qt][8] = MFMA16(ap[qt][m], vone, oacc[qt][8]);
        __builtin_amdgcn_s_setprio(0);
        SB0();

        // ---- late: write staged K tile to the other buffer ----
        {
            bf16* __restrict__ knxt = kb_lds + (cur ^ 1) * 8192;
#pragma unroll
            for (int c = 0; c < 4; c++)
                *(bf16x8*)(knxt + ((c * 4 + w) * 64 + lane) * 8) = kreg[c];
        }
        __syncthreads();
    }

    // ---- write fp32 partials (no cross-wave combine needed) ----
    const size_t pbase = (size_t)split * ROWS * D;
#pragma unroll
    for (int qt = 0; qt < 2; qt++) {
#pragma unroll
        for (int rg = 0; rg < 4; rg++) {
            const int row = (qtg0 + qt) * 16 + quad * 4 + rg;
            float* __restrict__ pr = po + pbase + (size_t)row * D;
#pragma unroll
            for (int t = 0; t < 8; t++)
                pr[t * 16 + l16] = oacc[qt][t][rg];
            if (l16 == 0) ps[split * ROWS + row] = oacc[qt][8][rg];
        }
    }
}

// ---------------------------------------------------------------------------
// comb: y = (P0 + P1) / (S0 + S1). Grid 2048 x 256, one float4 per thread.
// ---------------------------------------------------------------------------
__global__ __launch_bounds__(256) void comb(const float* __restrict__ po,
                                            const float* __restrict__ ps,
                                            float* __restrict__ y) {
    const int idx = blockIdx.x * 256 + threadIdx.x;  // 0..524287
    const int row = idx >> 5;
    const int c4 = idx & 31;
    const f32x4 a = *(const f32x4*)(po + (size_t)row * D + c4 * 4);
    const f32x4 b =
        *(const f32x4*)(po + (size_t)ROWS * D + (size_t)row * D + c4 * 4);
    const float rl = 1.0f / (ps[row] + ps[ROWS + row]);
    f32x4 r;
#pragma unroll
    for (int j = 0; j < 4; j++) r[j] = (a[j] + b[j]) * rl;
    *(f32x4*)(y + (size_t)row * D + c4 * 4) = r;
}

// ---------------------------------------------------------------------------
extern "C" void kernel_launch(void* const* d_in, const int* in_sizes, int n_in,
                              void* d_out, int out_size, void* d_ws, size_t ws_size,
                              hipStream_t stream) {
    const float* x = (const float*)d_in[0];
    const float* Wq = (const float*)d_in[1];
    const float* Wk = (const float*)d_in[2];
    const float* Wv = (const float*)d_in[3];
    float* y = (float*)d_out;

    bf16* qf = (bf16*)d_ws;            // 4MB
    bf16* kf = qf + (size_t)ROWS * D;  // 4MB
    bf16* vf = kf + (size_t)ROWS * D;  // 4MB (kappa-permuted fragment layout)
    float* po = (float*)(vf + (size_t)ROWS * D);  // 2 x 8.39MB fp32 partials
    float* ps = po + 2 * (size_t)ROWS * D;        // 2 x 64KB rowsums

    proj_all<<<768, 256, 0, stream>>>(x, Wq, Wk, Wv, qf, kf, vf);
    flash<<<256, 256, 0, stream>>>(qf, kf, vf, po, ps);
    comb<<<2048, 256, 0, stream>>>(po, ps, y);
}